// Round 1
// baseline (289.869 us; speedup 1.0000x reference)
//
#include <hip/hip_runtime.h>

typedef __attribute__((ext_vector_type(8))) short bf16x8;
typedef __attribute__((ext_vector_type(4))) float f32x4;
typedef __attribute__((ext_vector_type(8))) unsigned short ushort8;
typedef __attribute__((ext_vector_type(4))) unsigned short ushort4_t;

#define LSEQ 2048
#define NB 2
#define EMB 1024
#define NHEAD 16
#define HD 64

__device__ __forceinline__ unsigned short f2bf(float f) {
  unsigned u = __builtin_bit_cast(unsigned, f);
  u += 0x7fffu + ((u >> 16) & 1u);   // RNE (finite inputs only)
  return (unsigned short)(u >> 16);
}
__device__ __forceinline__ float bf2f(unsigned short s) {
  return __builtin_bit_cast(float, ((unsigned)s) << 16);
}

// async global->LDS, 16B per lane. LDS dest = wave-uniform base + lane*16.
__device__ __forceinline__ void gll16(const void* g, void* l) {
  __builtin_amdgcn_global_load_lds((const __attribute__((address_space(1))) unsigned*)g,
                                   (__attribute__((address_space(3))) unsigned*)l, 16, 0, 0);
}

// fp32 -> bf16 convert, vectorized float4 -> 4x bf16
__global__ __launch_bounds__(256) void cvt_f32_bf16(const float* __restrict__ in,
                                                    unsigned short* __restrict__ out, int n4) {
  int i = blockIdx.x * 256 + threadIdx.x;
  if (i >= n4) return;
  float4 v = ((const float4*)in)[i];
  ushort4_t o;
  o.x = f2bf(v.x); o.y = f2bf(v.y); o.z = f2bf(v.z); o.w = f2bf(v.w);
  ((ushort4_t*)out)[i] = o;
}

// C[M][Ncol] = A[M][K] * B[Ncol][K]^T + bias[col]   (NT GEMM, both K-contiguous)
// 128x128 tile, BK=64, 4 waves (2x2), each wave 64x64 = 4x4 frags of 16x16x32 bf16 MFMA.
template <bool OUT_BF16>
__global__ __launch_bounds__(256, 2) void gemm_bf16_nt(
    const unsigned short* __restrict__ A, const unsigned short* __restrict__ B,
    const float* __restrict__ bias, void* __restrict__ Cout, int M, int Ncol, int K) {
  __shared__ unsigned short Asm[128 * 64];
  __shared__ unsigned short Bsm[128 * 64];
  const int tid = threadIdx.x;
  const int wave = tid >> 6, lane = tid & 63;
  const int wr = (wave >> 1) * 64, wc = (wave & 1) * 64;
  const int lr = lane & 15, lg = lane >> 4;
  const int bm = blockIdx.x * 128, bn = blockIdx.y * 128;

  f32x4 acc[4][4];
#pragma unroll
  for (int i = 0; i < 4; ++i)
#pragma unroll
    for (int j = 0; j < 4; ++j) acc[i][j] = (f32x4){0.f, 0.f, 0.f, 0.f};

  for (int kt = 0; kt < K; kt += 64) {
    // stage A,B tiles: 128 rows x 64 k (128B rows), linear LDS, 16B/lane chunks
#pragma unroll
    for (int c = 0; c < 4; ++c) {
      int idx = (c * 4 + wave) * 64 + lane;
      int row = idx >> 3, ch = (idx & 7) * 8;
      gll16(A + (size_t)(bm + row) * K + kt + ch, &Asm[(c * 4 + wave) * 512]);
      gll16(B + (size_t)(bn + row) * K + kt + ch, &Bsm[(c * 4 + wave) * 512]);
    }
    __syncthreads();
#pragma unroll
    for (int ks = 0; ks < 2; ++ks) {
      bf16x8 af[4], bfr[4];
#pragma unroll
      for (int i = 0; i < 4; ++i)
        af[i] = *(const bf16x8*)&Asm[(wr + i * 16 + lr) * 64 + ks * 32 + lg * 8];
#pragma unroll
      for (int j = 0; j < 4; ++j)
        bfr[j] = *(const bf16x8*)&Bsm[(wc + j * 16 + lr) * 64 + ks * 32 + lg * 8];
#pragma unroll
      for (int i = 0; i < 4; ++i)
#pragma unroll
        for (int j = 0; j < 4; ++j)
          acc[i][j] = __builtin_amdgcn_mfma_f32_16x16x32_bf16(af[i], bfr[j], acc[i][j], 0, 0, 0);
    }
    __syncthreads();
  }
  // epilogue: C/D layout col=lane&15, row=(lane>>4)*4+reg
#pragma unroll
  for (int i = 0; i < 4; ++i) {
#pragma unroll
    for (int j = 0; j < 4; ++j) {
      int col = bn + wc + j * 16 + lr;
      float bv = bias[col];
#pragma unroll
      for (int r = 0; r < 4; ++r) {
        int row = bm + wr + i * 16 + lg * 4 + r;
        float v = acc[i][j][r] + bv;
        if constexpr (OUT_BF16)
          ((unsigned short*)Cout)[(size_t)row * Ncol + col] = f2bf(v);
        else
          ((float*)Cout)[(size_t)row * Ncol + col] = v;
      }
    }
  }
}

// V^T producer: vt[nh][d][l] (bf16) from qkv rows, 64x64 tiles through LDS
__global__ __launch_bounds__(256) void transpose_v(const unsigned short* __restrict__ qkv,
                                                   unsigned short* __restrict__ vt) {
  __shared__ unsigned short t[64][72];
  const int nh = blockIdx.y, n = nh >> 4, h = nh & 15;
  const int lt = blockIdx.x * 64;
  const int tid = threadIdx.x;
#pragma unroll
  for (int it = 0; it < 2; ++it) {
    int idx = it * 256 + tid;
    int l = idx >> 3, ch = (idx & 7) * 8;
    ushort8 v = *(const ushort8*)(qkv + (size_t)((lt + l) * NB + n) * 3072 + 2 * EMB + h * HD + ch);
    *(ushort8*)&t[l][ch] = v;
  }
  __syncthreads();
  int d = tid >> 2, lc = (tid & 3) * 16;
  unsigned short tmp[16];
#pragma unroll
  for (int i = 0; i < 16; ++i) tmp[i] = t[lc + i][d];
#pragma unroll
  for (int i = 0; i < 2; ++i)
    *(ushort8*)(vt + (size_t)(nh * HD + d) * LSEQ + lt + lc + i * 8) = *(const ushort8*)&tmp[i * 8];
}

// Flash attention: block = (q-tile of 64 rows) x (n,h). 4 waves x 16 q-rows.
// K tiles (64x64) + V^T tiles (64 d x 64 keys) staged via global_load_lds.
__global__ __launch_bounds__(256, 4) void flash_attn(const unsigned short* __restrict__ qkv,
                                                     const unsigned short* __restrict__ vt,
                                                     unsigned short* __restrict__ ob) {
  __shared__ unsigned short Ksm[64 * 64];
  __shared__ unsigned short Vsm[64 * 64];   // [d][key]
  __shared__ unsigned short Psm[4][16 * 72];
  const int tid = threadIdx.x, wave = tid >> 6, lane = tid & 63;
  const int lr = lane & 15, lg = lane >> 4;
  const int nh = blockIdx.y, n = nh >> 4, h = nh & 15;
  const int q0 = blockIdx.x * 64 + wave * 16;

  // Q fragments direct from global, pre-scaled by 1/sqrt(D)=0.125 (exact in bf16)
  bf16x8 qf[2];
  {
    const unsigned short* qb = qkv + (size_t)((q0 + lr) * NB + n) * 3072 + h * HD + lg * 8;
#pragma unroll
    for (int ks = 0; ks < 2; ++ks) {
      bf16x8 tv = *(const bf16x8*)(qb + ks * 32);
#pragma unroll
      for (int e = 0; e < 8; ++e) {
        float f = bf2f((unsigned short)tv[e]) * 0.125f;
        tv[e] = (short)f2bf(f);
      }
      qf[ks] = tv;
    }
  }

  float m[4], lsum[4];
  f32x4 o[4];
#pragma unroll
  for (int r = 0; r < 4; ++r) { m[r] = -1e30f; lsum[r] = 0.f; }
#pragma unroll
  for (int d = 0; d < 4; ++d) o[d] = (f32x4){0.f, 0.f, 0.f, 0.f};

  for (int kt = 0; kt < LSEQ / 64; ++kt) {
    // stage K tile (rows=key, 128B) and V^T tile (rows=d, 128B)
#pragma unroll
    for (int c = 0; c < 2; ++c) {
      int idx = (c * 4 + wave) * 64 + lane;
      int row = idx >> 3, ch = (idx & 7) * 8;
      gll16(qkv + (size_t)((kt * 64 + row) * NB + n) * 3072 + EMB + h * HD + ch,
            &Ksm[(c * 4 + wave) * 512]);
      gll16(vt + (size_t)(nh * HD + row) * LSEQ + kt * 64 + ch,
            &Vsm[(c * 4 + wave) * 512]);
    }
    __syncthreads();

    // S = (Q*scale) K^T : rows=q, cols=key
    f32x4 s[4];
#pragma unroll
    for (int j = 0; j < 4; ++j) s[j] = (f32x4){0.f, 0.f, 0.f, 0.f};
#pragma unroll
    for (int ks = 0; ks < 2; ++ks) {
#pragma unroll
      for (int j = 0; j < 4; ++j) {
        bf16x8 kf = *(const bf16x8*)&Ksm[(j * 16 + lr) * 64 + ks * 32 + lg * 8];
        s[j] = __builtin_amdgcn_mfma_f32_16x16x32_bf16(qf[ks], kf, s[j], 0, 0, 0);
      }
    }

    // online softmax (per q-row; rows live as reg r within 16-lane group lg)
    float mx[4];
#pragma unroll
    for (int r = 0; r < 4; ++r)
      mx[r] = fmaxf(fmaxf(s[0][r], s[1][r]), fmaxf(s[2][r], s[3][r]));
#pragma unroll
    for (int off = 1; off < 16; off <<= 1)
#pragma unroll
      for (int r = 0; r < 4; ++r) mx[r] = fmaxf(mx[r], __shfl_xor(mx[r], off));
    float al[4];
#pragma unroll
    for (int r = 0; r < 4; ++r) {
      float mn = fmaxf(m[r], mx[r]);
      al[r] = __expf(m[r] - mn);
      m[r] = mn;
    }
    float ps[4] = {0.f, 0.f, 0.f, 0.f};
#pragma unroll
    for (int j = 0; j < 4; ++j)
#pragma unroll
      for (int r = 0; r < 4; ++r) {
        float p = __expf(s[j][r] - m[r]);
        s[j][r] = p;
        ps[r] += p;
      }
#pragma unroll
    for (int off = 1; off < 16; off <<= 1)
#pragma unroll
      for (int r = 0; r < 4; ++r) ps[r] += __shfl_xor(ps[r], off);
#pragma unroll
    for (int r = 0; r < 4; ++r) lsum[r] = lsum[r] * al[r] + ps[r];
#pragma unroll
    for (int d = 0; d < 4; ++d)
#pragma unroll
      for (int r = 0; r < 4; ++r) o[d][r] *= al[r];

    // P -> per-wave LDS (bf16), then PV
#pragma unroll
    for (int j = 0; j < 4; ++j)
#pragma unroll
      for (int r = 0; r < 4; ++r)
        Psm[wave][(lg * 4 + r) * 72 + j * 16 + lr] = f2bf(s[j][r]);
#pragma unroll
    for (int ks = 0; ks < 2; ++ks) {
      bf16x8 pf = *(const bf16x8*)&Psm[wave][lr * 72 + ks * 32 + lg * 8];
#pragma unroll
      for (int d = 0; d < 4; ++d) {
        bf16x8 vf = *(const bf16x8*)&Vsm[(d * 16 + lr) * 64 + ks * 32 + lg * 8];
        o[d] = __builtin_amdgcn_mfma_f32_16x16x32_bf16(pf, vf, o[d], 0, 0, 0);
      }
    }
    __syncthreads();
  }

  // normalize + write O rows as bf16 (row q, col h*64+d)
#pragma unroll
  for (int r = 0; r < 4; ++r) {
    float inv = 1.0f / lsum[r];
    int q = q0 + lg * 4 + r;
#pragma unroll
    for (int d = 0; d < 4; ++d)
      ob[(size_t)(q * NB + n) * EMB + h * HD + d * 16 + lr] = f2bf(o[d][r] * inv);
  }
}

extern "C" void kernel_launch(void* const* d_in, const int* in_sizes, int n_in,
                              void* d_out, int out_size, void* d_ws, size_t ws_size,
                              hipStream_t stream) {
  const float* x = (const float*)d_in[0];
  const float* wqkv = (const float*)d_in[1];
  const float* bqkv = (const float*)d_in[2];
  const float* wout = (const float*)d_in[3];
  const float* bout = (const float*)d_in[4];

  char* ws = (char*)d_ws;
  unsigned short* xb    = (unsigned short*)(ws);              //  8 MB: x bf16 [4096][1024]
  unsigned short* wqkvb = (unsigned short*)(ws + 8388608);    //  6 MB: Wqkv bf16 [3072][1024]
  unsigned short* woutb = (unsigned short*)(ws + 14680064);   //  2 MB: Wout bf16 [1024][1024]
  unsigned short* qkvb  = (unsigned short*)(ws + 16777216);   // 24 MB: qkv bf16 [4096][3072]
  unsigned short* vtb   = (unsigned short*)(ws + 41943040);   //  8 MB: V^T bf16 [32][64][2048]
  unsigned short* obuf  = (unsigned short*)(ws + 50331648);   //  8 MB: attn out bf16 [4096][1024]

  cvt_f32_bf16<<<4096, 256, 0, stream>>>(x, xb, 1048576);
  cvt_f32_bf16<<<3072, 256, 0, stream>>>(wqkv, wqkvb, 786432);
  cvt_f32_bf16<<<1024, 256, 0, stream>>>(wout, woutb, 262144);

  dim3 g1(32, 24);
  gemm_bf16_nt<true><<<g1, 256, 0, stream>>>(xb, wqkvb, bqkv, qkvb, 4096, 3072, 1024);

  dim3 g2(32, 32);
  transpose_v<<<g2, 256, 0, stream>>>(qkvb, vtb);
  flash_attn<<<g2, 256, 0, stream>>>(qkvb, vtb, obuf);

  dim3 g3(32, 8);
  gemm_bf16_nt<false><<<g3, 256, 0, stream>>>(obuf, woutb, bout, d_out, 4096, 1024, 1024);
}

// Round 2
// 259.122 us; speedup vs baseline: 1.1187x; 1.1187x over previous
//
#include <hip/hip_runtime.h>

typedef __attribute__((ext_vector_type(8))) short bf16x8;
typedef __attribute__((ext_vector_type(4))) float f32x4;
typedef __attribute__((ext_vector_type(8))) unsigned short ushort8;
typedef __attribute__((ext_vector_type(4))) unsigned short ushort4_t;

#define LSEQ 2048
#define NB 2
#define EMB 1024
#define NHEAD 16
#define HD 64

__device__ __forceinline__ unsigned short f2bf(float f) {
  unsigned u = __builtin_bit_cast(unsigned, f);
  u += 0x7fffu + ((u >> 16) & 1u);   // RNE (finite inputs only)
  return (unsigned short)(u >> 16);
}
__device__ __forceinline__ float bf2f(unsigned short s) {
  return __builtin_bit_cast(float, ((unsigned)s) << 16);
}

// async global->LDS, 16B per lane. LDS dest = wave-uniform base + lane*16.
__device__ __forceinline__ void gll16(const void* g, void* l) {
  __builtin_amdgcn_global_load_lds((const __attribute__((address_space(1))) unsigned*)g,
                                   (__attribute__((address_space(3))) unsigned*)l, 16, 0, 0);
}

// fp32 -> bf16 convert, vectorized float4 -> 4x bf16
__global__ __launch_bounds__(256) void cvt_f32_bf16(const float* __restrict__ in,
                                                    unsigned short* __restrict__ out, int n4) {
  int i = blockIdx.x * 256 + threadIdx.x;
  if (i >= n4) return;
  float4 v = ((const float4*)in)[i];
  ushort4_t o;
  o.x = f2bf(v.x); o.y = f2bf(v.y); o.z = f2bf(v.z); o.w = f2bf(v.w);
  ((ushort4_t*)out)[i] = o;
}

// C[M][Ncol] = A[M][K] * B[Ncol][K]^T + bias[col]   (NT GEMM, both K-contiguous)
// 128x128 tile, BK=64, 4 waves (2x2), each wave 64x64 = 4x4 frags of 16x16x32 bf16 MFMA.
template <bool OUT_BF16>
__global__ __launch_bounds__(256, 2) void gemm_bf16_nt(
    const unsigned short* __restrict__ A, const unsigned short* __restrict__ B,
    const float* __restrict__ bias, void* __restrict__ Cout, int M, int Ncol, int K) {
  __shared__ unsigned short Asm[128 * 64];
  __shared__ unsigned short Bsm[128 * 64];
  const int tid = threadIdx.x;
  const int wave = tid >> 6, lane = tid & 63;
  const int wr = (wave >> 1) * 64, wc = (wave & 1) * 64;
  const int lr = lane & 15, lg = lane >> 4;
  const int bm = blockIdx.x * 128, bn = blockIdx.y * 128;

  f32x4 acc[4][4];
#pragma unroll
  for (int i = 0; i < 4; ++i)
#pragma unroll
    for (int j = 0; j < 4; ++j) acc[i][j] = (f32x4){0.f, 0.f, 0.f, 0.f};

  for (int kt = 0; kt < K; kt += 64) {
    // stage A,B tiles: 128 rows x 64 k (128B rows), linear LDS, 16B/lane chunks
#pragma unroll
    for (int c = 0; c < 4; ++c) {
      int idx = (c * 4 + wave) * 64 + lane;
      int row = idx >> 3, ch = (idx & 7) * 8;
      gll16(A + (size_t)(bm + row) * K + kt + ch, &Asm[(c * 4 + wave) * 512]);
      gll16(B + (size_t)(bn + row) * K + kt + ch, &Bsm[(c * 4 + wave) * 512]);
    }
    __syncthreads();
#pragma unroll
    for (int ks = 0; ks < 2; ++ks) {
      bf16x8 af[4], bfr[4];
#pragma unroll
      for (int i = 0; i < 4; ++i)
        af[i] = *(const bf16x8*)&Asm[(wr + i * 16 + lr) * 64 + ks * 32 + lg * 8];
#pragma unroll
      for (int j = 0; j < 4; ++j)
        bfr[j] = *(const bf16x8*)&Bsm[(wc + j * 16 + lr) * 64 + ks * 32 + lg * 8];
#pragma unroll
      for (int i = 0; i < 4; ++i)
#pragma unroll
        for (int j = 0; j < 4; ++j)
          acc[i][j] = __builtin_amdgcn_mfma_f32_16x16x32_bf16(af[i], bfr[j], acc[i][j], 0, 0, 0);
    }
    __syncthreads();
  }
  // epilogue: C/D layout col=lane&15, row=(lane>>4)*4+reg
#pragma unroll
  for (int i = 0; i < 4; ++i) {
#pragma unroll
    for (int j = 0; j < 4; ++j) {
      int col = bn + wc + j * 16 + lr;
      float bv = bias[col];
#pragma unroll
      for (int r = 0; r < 4; ++r) {
        int row = bm + wr + i * 16 + lg * 4 + r;
        float v = acc[i][j][r] + bv;
        if constexpr (OUT_BF16)
          ((unsigned short*)Cout)[(size_t)row * Ncol + col] = f2bf(v);
        else
          ((float*)Cout)[(size_t)row * Ncol + col] = v;
      }
    }
  }
}

// V^T producer: vt[nh][d][l] (bf16) from qkv rows, 64x64 tiles through LDS
__global__ __launch_bounds__(256) void transpose_v(const unsigned short* __restrict__ qkv,
                                                   unsigned short* __restrict__ vt) {
  __shared__ unsigned short t[64][72];
  const int nh = blockIdx.y, n = nh >> 4, h = nh & 15;
  const int lt = blockIdx.x * 64;
  const int tid = threadIdx.x;
#pragma unroll
  for (int it = 0; it < 2; ++it) {
    int idx = it * 256 + tid;
    int l = idx >> 3, ch = (idx & 7) * 8;
    ushort8 v = *(const ushort8*)(qkv + (size_t)((lt + l) * NB + n) * 3072 + 2 * EMB + h * HD + ch);
    *(ushort8*)&t[l][ch] = v;
  }
  __syncthreads();
  int d = tid >> 2, lc = (tid & 3) * 16;
  unsigned short tmp[16];
#pragma unroll
  for (int i = 0; i < 16; ++i) tmp[i] = t[lc + i][d];
#pragma unroll
  for (int i = 0; i < 2; ++i)
    *(ushort8*)(vt + (size_t)(nh * HD + d) * LSEQ + lt + lc + i * 8) = *(const ushort8*)&tmp[i * 8];
}

// Flash attention: block = (q-tile of 64 rows) x (n,h). 4 waves x 16 q-rows.
// K tiles (64x64) + V^T tiles (64 d x 64 keys) staged via global_load_lds.
// LDS is XOR-swizzled (T2 via rule #21): global SOURCE chunk is pre-swizzled
// (gload_lds writes linearly), reads XOR the chunk index with (row&7).
__global__ __launch_bounds__(256, 4) void flash_attn(const unsigned short* __restrict__ qkv,
                                                     const unsigned short* __restrict__ vt,
                                                     unsigned short* __restrict__ ob) {
  __shared__ unsigned short Ksm[64 * 64];
  __shared__ unsigned short Vsm[64 * 64];   // [d][key]
  __shared__ unsigned short Psm[4][16 * 72];
  const int tid = threadIdx.x, wave = tid >> 6, lane = tid & 63;
  const int lr = lane & 15, lg = lane >> 4;
  const int nh = blockIdx.y, n = nh >> 4, h = nh & 15;
  const int q0 = blockIdx.x * 64 + wave * 16;

  // staging swizzle: lane stages LDS chunk (lane&7) of row (base + lane>>3);
  // source global chunk = (lane&7) ^ (row&7); (row&7) == ((lane>>3)&7) since
  // each wave-call covers 8 aligned rows.
  const int sch = ((lane & 7) ^ ((lane >> 3) & 7)) * 8;

  // Q fragments direct from global, pre-scaled by 1/sqrt(D)=0.125 (exact in bf16)
  bf16x8 qf[2];
  {
    const unsigned short* qb = qkv + (size_t)((q0 + lr) * NB + n) * 3072 + h * HD + lg * 8;
#pragma unroll
    for (int ks = 0; ks < 2; ++ks) {
      bf16x8 tv = *(const bf16x8*)(qb + ks * 32);
#pragma unroll
      for (int e = 0; e < 8; ++e) {
        float f = bf2f((unsigned short)tv[e]) * 0.125f;
        tv[e] = (short)f2bf(f);
      }
      qf[ks] = tv;
    }
  }

  float m[4], lsum[4];
  f32x4 o[4];
#pragma unroll
  for (int r = 0; r < 4; ++r) { m[r] = -1e30f; lsum[r] = 0.f; }
#pragma unroll
  for (int d = 0; d < 4; ++d) o[d] = (f32x4){0.f, 0.f, 0.f, 0.f};

  for (int kt = 0; kt < LSEQ / 64; ++kt) {
    // stage K tile (rows=key, 128B) and V^T tile (rows=d, 128B), source pre-swizzled
#pragma unroll
    for (int c = 0; c < 2; ++c) {
      int idx = (c * 4 + wave) * 64 + lane;
      int row = idx >> 3;
      gll16(qkv + (size_t)((kt * 64 + row) * NB + n) * 3072 + EMB + h * HD + sch,
            &Ksm[(c * 4 + wave) * 512]);
      gll16(vt + (size_t)(nh * HD + row) * LSEQ + kt * 64 + sch,
            &Vsm[(c * 4 + wave) * 512]);
    }
    __syncthreads();

    // S = (Q*scale) K^T : rows=q, cols=key  (swizzled K read)
    f32x4 s[4];
#pragma unroll
    for (int j = 0; j < 4; ++j) s[j] = (f32x4){0.f, 0.f, 0.f, 0.f};
#pragma unroll
    for (int ks = 0; ks < 2; ++ks) {
#pragma unroll
      for (int j = 0; j < 4; ++j) {
        bf16x8 kf = *(const bf16x8*)&Ksm[(j * 16 + lr) * 64 + ((ks * 4 + lg) ^ (lr & 7)) * 8];
        s[j] = __builtin_amdgcn_mfma_f32_16x16x32_bf16(qf[ks], kf, s[j], 0, 0, 0);
      }
    }

    // online softmax (per q-row; rows live as reg r within 16-lane group lg)
    float mx[4];
#pragma unroll
    for (int r = 0; r < 4; ++r)
      mx[r] = fmaxf(fmaxf(s[0][r], s[1][r]), fmaxf(s[2][r], s[3][r]));
#pragma unroll
    for (int off = 1; off < 16; off <<= 1)
#pragma unroll
      for (int r = 0; r < 4; ++r) mx[r] = fmaxf(mx[r], __shfl_xor(mx[r], off));
    float al[4];
#pragma unroll
    for (int r = 0; r < 4; ++r) {
      float mn = fmaxf(m[r], mx[r]);
      al[r] = __expf(m[r] - mn);
      m[r] = mn;
    }
    float ps[4] = {0.f, 0.f, 0.f, 0.f};
#pragma unroll
    for (int j = 0; j < 4; ++j)
#pragma unroll
      for (int r = 0; r < 4; ++r) {
        float p = __expf(s[j][r] - m[r]);
        s[j][r] = p;
        ps[r] += p;
      }
#pragma unroll
    for (int off = 1; off < 16; off <<= 1)
#pragma unroll
      for (int r = 0; r < 4; ++r) ps[r] += __shfl_xor(ps[r], off);
#pragma unroll
    for (int r = 0; r < 4; ++r) lsum[r] = lsum[r] * al[r] + ps[r];
#pragma unroll
    for (int d = 0; d < 4; ++d)
#pragma unroll
      for (int r = 0; r < 4; ++r) o[d][r] *= al[r];

    // P -> per-wave LDS (bf16), then PV (swizzled V read)
#pragma unroll
    for (int j = 0; j < 4; ++j)
#pragma unroll
      for (int r = 0; r < 4; ++r)
        Psm[wave][(lg * 4 + r) * 72 + j * 16 + lr] = f2bf(s[j][r]);
#pragma unroll
    for (int ks = 0; ks < 2; ++ks) {
      bf16x8 pf = *(const bf16x8*)&Psm[wave][lr * 72 + ks * 32 + lg * 8];
#pragma unroll
      for (int d = 0; d < 4; ++d) {
        bf16x8 vf = *(const bf16x8*)&Vsm[(d * 16 + lr) * 64 + ((ks * 4 + lg) ^ (lr & 7)) * 8];
        o[d] = __builtin_amdgcn_mfma_f32_16x16x32_bf16(pf, vf, o[d], 0, 0, 0);
      }
    }
    __syncthreads();
  }

  // normalize + write O rows as bf16 (row q, col h*64+d)
#pragma unroll
  for (int r = 0; r < 4; ++r) {
    float inv = 1.0f / lsum[r];
    int q = q0 + lg * 4 + r;
#pragma unroll
    for (int d = 0; d < 4; ++d)
      ob[(size_t)(q * NB + n) * EMB + h * HD + d * 16 + lr] = f2bf(o[d][r] * inv);
  }
}

extern "C" void kernel_launch(void* const* d_in, const int* in_sizes, int n_in,
                              void* d_out, int out_size, void* d_ws, size_t ws_size,
                              hipStream_t stream) {
  const float* x = (const float*)d_in[0];
  const float* wqkv = (const float*)d_in[1];
  const float* bqkv = (const float*)d_in[2];
  const float* wout = (const float*)d_in[3];
  const float* bout = (const float*)d_in[4];

  char* ws = (char*)d_ws;
  unsigned short* xb    = (unsigned short*)(ws);              //  8 MB: x bf16 [4096][1024]
  unsigned short* wqkvb = (unsigned short*)(ws + 8388608);    //  6 MB: Wqkv bf16 [3072][1024]
  unsigned short* woutb = (unsigned short*)(ws + 14680064);   //  2 MB: Wout bf16 [1024][1024]
  unsigned short* qkvb  = (unsigned short*)(ws + 16777216);   // 24 MB: qkv bf16 [4096][3072]
  unsigned short* vtb   = (unsigned short*)(ws + 41943040);   //  8 MB: V^T bf16 [32][64][2048]
  unsigned short* obuf  = (unsigned short*)(ws + 50331648);   //  8 MB: attn out bf16 [4096][1024]

  cvt_f32_bf16<<<4096, 256, 0, stream>>>(x, xb, 1048576);
  cvt_f32_bf16<<<3072, 256, 0, stream>>>(wqkv, wqkvb, 786432);
  cvt_f32_bf16<<<1024, 256, 0, stream>>>(wout, woutb, 262144);

  dim3 g1(32, 24);
  gemm_bf16_nt<true><<<g1, 256, 0, stream>>>(xb, wqkvb, bqkv, qkvb, 4096, 3072, 1024);

  dim3 g2(32, 32);
  transpose_v<<<g2, 256, 0, stream>>>(qkvb, vtb);
  flash_attn<<<g2, 256, 0, stream>>>(qkvb, vtb, obuf);

  dim3 g3(32, 8);
  gemm_bf16_nt<false><<<g3, 256, 0, stream>>>(obuf, woutb, bout, d_out, 4096, 1024, 1024);
}